// Round 2
// baseline (658.027 us; speedup 1.0000x reference)
//
#include <hip/hip_runtime.h>
#include <math.h>
#include <stdint.h>

#define LDIM 4096   // L = 64*64
#define NC   256
#define W66  66
#define P66  4356   // 66*66
#define BZ   4
#define EPSK 1e-7f

typedef _Float16 v8h __attribute__((ext_vector_type(8)));
typedef float v4f __attribute__((ext_vector_type(4)));

__device__ __forceinline__ void cp16(const void* g, void* l) {
    __builtin_amdgcn_global_load_lds(
        (const __attribute__((address_space(1))) void*)g,
        (__attribute__((address_space(3))) void*)l, 16, 0, 0);
}

// ---------------- rnorm: 1/||x[:,l]+eps|| per (b,l) ----------------
__global__ __launch_bounds__(256) void rnorm_kernel(const float* __restrict__ x,
                                                    float* __restrict__ rnorm) {
    int idx = blockIdx.x * 256 + threadIdx.x;      // over BZ*LDIM = 16384
    int b = idx >> 12;
    int l = idx & (LDIM - 1);
    const float* xb = x + (size_t)b * NC * LDIM + l;
    float s = 0.f;
#pragma unroll 8
    for (int c = 0; c < NC; ++c) {
        float v = xb[(size_t)c * LDIM] + EPSK;
        s += v * v;
    }
    rnorm[idx] = 1.0f / sqrtf(s);
}

// ---------------- kconv: Kcl[b][c][l] fp16 and Klc[b][l][c] fp16 ----------------
__global__ __launch_bounds__(256) void kconv_kernel(const float* __restrict__ x,
                                                    const float* __restrict__ rn,
                                                    _Float16* __restrict__ Kcl,
                                                    _Float16* __restrict__ Klc) {
    __shared__ _Float16 t[64][72];
    int b = blockIdx.z, c0 = blockIdx.y * 64, l0 = blockIdx.x * 64;
    int tid = threadIdx.x;
    int r = tid >> 2, q = (tid & 3) * 16;
    const float* xr = x + ((size_t)(b * NC + c0 + r)) * LDIM + l0 + q;
    const float* rr = rn + b * LDIM + l0 + q;
    _Float16 h[16];
#pragma unroll
    for (int j = 0; j < 16; ++j)
        h[j] = (_Float16)((xr[j] + EPSK) * rr[j]);
    _Float16* kc = Kcl + ((size_t)(b * NC + c0 + r)) * LDIM + l0 + q;
    *(v8h*)kc = *(v8h*)h;
    *(v8h*)(kc + 8) = *(v8h*)(h + 8);
#pragma unroll
    for (int j = 0; j < 16; ++j) t[r][q + j] = h[j];
    __syncthreads();
    _Float16 g[16];
#pragma unroll
    for (int j = 0; j < 16; ++j) g[j] = t[q + j][r];
    _Float16* kl = Klc + ((size_t)(b * LDIM + l0 + r)) * NC + c0 + q;
    *(v8h*)kl = *(v8h*)g;
    *(v8h*)(kl + 8) = *(v8h*)(g + 8);
}

// ---------------- pool: PoolF[b][c][p] fp32, 3x3 clipped sum ----------------
__global__ __launch_bounds__(256) void pool_kernel(const float* __restrict__ x,
                                                   float* __restrict__ Pm) {
    size_t idx = (size_t)blockIdx.x * 256 + threadIdx.x;  // over BZ*NC*P66
    int p = (int)(idx % P66);
    size_t bc = idx / P66;
    int u = p / W66, v = p % W66;
    const float* xbc = x + bc * (size_t)LDIM;
    int i0 = max(u - 2, 0), i1 = min(u, 63);
    int j0 = max(v - 2, 0), j1 = min(v, 63);
    float s = 0.f;
    for (int i = i0; i <= i1; ++i)
        for (int j = j0; j <= j1; ++j)
            s += xbc[i * 64 + j];
    Pm[idx] = s;
}

// ---------------- ptrans: Pm16[b][p][c] fp16 = transpose(PoolF) ----------------
__global__ __launch_bounds__(256) void ptrans_kernel(const float* __restrict__ PoolF,
                                                     _Float16* __restrict__ Pm16) {
    __shared__ float t[64][65];
    int b = blockIdx.z, c0 = blockIdx.y * 64, p0 = blockIdx.x * 64;
    int tid = threadIdx.x;
    int r = tid >> 2, q = (tid & 3) * 16;
    const float* src = PoolF + ((size_t)(b * NC + c0 + r)) * P66 + p0 + q;
#pragma unroll
    for (int j = 0; j < 16; ++j) t[r][q + j] = src[j];  // overread lands in next ws region (safe)
    __syncthreads();
    if (p0 + r < P66) {
        _Float16 g[16];
#pragma unroll
        for (int j = 0; j < 16; ++j) g[j] = (_Float16)t[q + j][r];
        _Float16* dst = Pm16 + ((size_t)(b * P66 + p0 + r)) * NC + c0 + q;
        *(v8h*)dst = *(v8h*)g;
        *(v8h*)(dst + 8) = *(v8h*)(g + 8);
    }
}

// ---------------- GEMM1 (MFMA fp16): S[p][l] = sum_c Pm16[p][c]*Klc[l][c] ----------------
__global__ __launch_bounds__(256) void gemm1_mfma(const _Float16* __restrict__ Pm16,
                                                  const _Float16* __restrict__ Klc,
                                                  float* __restrict__ S) {
    __shared__ _Float16 As[128 * 32];
    __shared__ _Float16 Bs[128 * 32];
    int b = blockIdx.z;
    int p0 = blockIdx.y * 128;
    int l0 = blockIdx.x * 128;
    const _Float16* A = Pm16 + (size_t)b * P66 * NC;
    const _Float16* B = Klc + (size_t)b * LDIM * NC;
    float* C = S + (size_t)b * P66 * LDIM;
    int tid = threadIdx.x;
    int lane = tid & 63, wave = tid >> 6;
    int wm = (wave >> 1) * 64, wn = (wave & 1) * 64;
    int quad = lane >> 4, hn = lane & 15;
    int sr = tid >> 2, sk = (tid & 3) * 8;
    int pa0 = p0 + sr;      if (pa0 > P66 - 1) pa0 = P66 - 1;
    int pa1 = p0 + sr + 64; if (pa1 > P66 - 1) pa1 = P66 - 1;
    const _Float16* Ag0 = A + (size_t)pa0 * NC + sk;
    const _Float16* Ag1 = A + (size_t)pa1 * NC + sk;
    const _Float16* Bg0 = B + (size_t)(l0 + sr) * NC + sk;
    const _Float16* Bg1 = B + (size_t)(l0 + sr + 64) * NC + sk;
    char* lA = (char*)As + tid * 16;
    char* lB = (char*)Bs + tid * 16;
    v4f acc[4][4];
    v4f vz = {0.f, 0.f, 0.f, 0.f};
#pragma unroll
    for (int i = 0; i < 4; ++i)
#pragma unroll
        for (int j = 0; j < 4; ++j) acc[i][j] = vz;

    for (int k0 = 0; k0 < NC; k0 += 32) {
        __syncthreads();
        cp16(Ag0 + k0, lA);
        cp16(Ag1 + k0, lA + 4096);
        cp16(Bg0 + k0, lB);
        cp16(Bg1 + k0, lB + 4096);
        __syncthreads();
        v8h af[4], bfr[4];
#pragma unroll
        for (int t = 0; t < 4; ++t)
            af[t] = *(const v8h*)(As + (wm + t * 16 + hn) * 32 + quad * 8);
#pragma unroll
        for (int t = 0; t < 4; ++t)
            bfr[t] = *(const v8h*)(Bs + (wn + t * 16 + hn) * 32 + quad * 8);
#pragma unroll
        for (int i = 0; i < 4; ++i)
#pragma unroll
            for (int j = 0; j < 4; ++j)
                acc[i][j] = __builtin_amdgcn_mfma_f32_16x16x32_f16(af[i], bfr[j], acc[i][j], 0, 0, 0);
    }
#pragma unroll
    for (int i = 0; i < 4; ++i) {
        int pr = p0 + wm + i * 16 + quad * 4;
#pragma unroll
        for (int j = 0; j < 4; ++j) {
            int lc = l0 + wn + j * 16 + hn;
            float* Cp = C + (size_t)pr * LDIM + lc;
#pragma unroll
            for (int r = 0; r < 4; ++r)
                if (pr + r < P66) Cp[(size_t)r * LDIM] = acc[i][j][r];
        }
    }
}

// ---------------- softmax over l, in place on att rows ----------------
__global__ __launch_bounds__(256) void softmax_kernel(float* __restrict__ att) {
    float* row = att + (size_t)blockIdx.x * LDIM;
    int tid = threadIdx.x;
    float4 v[4];
    float mx = -1e30f;
#pragma unroll
    for (int i = 0; i < 4; ++i) {
        v[i] = ((float4*)row)[tid + i * 256];
        mx = fmaxf(mx, fmaxf(fmaxf(v[i].x, v[i].y), fmaxf(v[i].z, v[i].w)));
    }
    __shared__ float sred[4];
    __shared__ float ssum[4];
#pragma unroll
    for (int off = 32; off > 0; off >>= 1) mx = fmaxf(mx, __shfl_xor(mx, off));
    if ((tid & 63) == 0) sred[tid >> 6] = mx;
    __syncthreads();
    float m4 = fmaxf(fmaxf(sred[0], sred[1]), fmaxf(sred[2], sred[3]));
    float sum = 0.f;
#pragma unroll
    for (int i = 0; i < 4; ++i) {
        v[i].x = __expf(v[i].x - m4);
        v[i].y = __expf(v[i].y - m4);
        v[i].z = __expf(v[i].z - m4);
        v[i].w = __expf(v[i].w - m4);
        sum += (v[i].x + v[i].y) + (v[i].z + v[i].w);
    }
#pragma unroll
    for (int off = 32; off > 0; off >>= 1) sum += __shfl_xor(sum, off);
    if ((tid & 63) == 0) ssum[tid >> 6] = sum;
    __syncthreads();
    float r = 1.0f / (ssum[0] + ssum[1] + ssum[2] + ssum[3]);
#pragma unroll
    for (int i = 0; i < 4; ++i) {
        v[i].x *= r; v[i].y *= r; v[i].z *= r; v[i].w *= r;
        ((float4*)row)[tid + i * 256] = v[i];
    }
}

// ---------------- GEMM2 (MFMA fp16): out[c][i] = sum_l Kcl[c][l]*att[p(i)][l] ----------------
// Output-split tiling: 128(c) x 32(i) tiles -> grid 2 x 128 x 4 = 1024 blocks (~7 blocks/CU by
// LDS=12KiB + VGPR), write-only stores to out (no atomics). B (att) f32 tile is XOR-swizzled
// (pre-swizzled per-lane GLOBAL source + swizzled read; LDS dest stays linear for global_load_lds)
// to kill the 16-way bank conflict of 128-B rows.
__global__ __launch_bounds__(256) void gemm2_mfma(const _Float16* __restrict__ Kcl,
                                                  const float* __restrict__ attF,
                                                  float* __restrict__ outp) {
    __shared__ _Float16 As[128 * 32];   // 8 KiB: 128 c-rows x 32 K
    __shared__ float BsF[32 * 32];      // 4 KiB: 32 i-rows x 32 K (swizzled 16B slots)
    int b = blockIdx.z;
    int c0 = blockIdx.x * 128;
    int i0 = blockIdx.y * 32;
    const _Float16* A = Kcl + (size_t)b * NC * LDIM;
    const float* Batt = attF + (size_t)b * P66 * LDIM;
    float* C = outp + (size_t)b * NC * LDIM;
    int tid = threadIdx.x;
    int lane = tid & 63, wave = tid >> 6;
    int wm = (wave >> 1) * 64, wn = (wave & 1) * 16;
    int quad = lane >> 4, hn = lane & 15;
    int sr = tid >> 2, sk = (tid & 3) * 8;
    const _Float16* Ag0 = A + (size_t)(c0 + sr) * LDIM + sk;
    const _Float16* Ag1 = A + (size_t)(c0 + sr + 64) * LDIM + sk;
    // B staging: thread -> row br (0..31), 16B slot (tid&7); source col slot XOR'd by row
    // so that the LINEAR LDS write leaves slot s holding source slot s^(br&7).
    int br = tid >> 3;
    int bo = (((tid & 7) ^ (br & 7)) << 2);      // floats
    int ii = i0 + br;
    int p = ((ii >> 6) + 1) * W66 + (ii & 63) + 1;
    const float* Bg = Batt + (size_t)p * LDIM + bo;
    char* lA = (char*)As + tid * 16;
    char* lB = (char*)BsF + tid * 16;
    v4f acc[4];
    v4f vz = {0.f, 0.f, 0.f, 0.f};
#pragma unroll
    for (int i = 0; i < 4; ++i) acc[i] = vz;

    for (int k0 = 0; k0 < LDIM; k0 += 32) {
        __syncthreads();
        cp16(Ag0 + k0, lA);
        cp16(Ag1 + k0, lA + 4096);
        cp16(Bg + k0, lB);
        __syncthreads();
        v8h af[4];
#pragma unroll
        for (int t = 0; t < 4; ++t)
            af[t] = *(const v8h*)(As + (wm + t * 16 + hn) * 32 + quad * 8);
        int brow = wn + hn;                      // 0..31
        int s0 = ((quad * 2 + 0) ^ (brow & 7)) << 2;
        int s1 = ((quad * 2 + 1) ^ (brow & 7)) << 2;
        v4f x0 = *(const v4f*)(BsF + brow * 32 + s0);
        v4f x1 = *(const v4f*)(BsF + brow * 32 + s1);
        v8h bfr;
#pragma unroll
        for (int j = 0; j < 4; ++j) { bfr[j] = (_Float16)x0[j]; bfr[j + 4] = (_Float16)x1[j]; }
#pragma unroll
        for (int i = 0; i < 4; ++i)
            acc[i] = __builtin_amdgcn_mfma_f32_16x16x32_f16(af[i], bfr, acc[i], 0, 0, 0);
    }
#pragma unroll
    for (int i = 0; i < 4; ++i) {
        int cr = c0 + wm + i * 16 + quad * 4;
        int ic = i0 + wn + hn;
        float* Cp = C + (size_t)cr * LDIM + ic;
#pragma unroll
        for (int r = 0; r < 4; ++r)
            Cp[(size_t)r * LDIM] = acc[i][r];
    }
}

extern "C" void kernel_launch(void* const* d_in, const int* in_sizes, int n_in,
                              void* d_out, int out_size, void* d_ws, size_t ws_size,
                              hipStream_t stream) {
    const float* x = (const float*)d_in[0];       // [4,256,64,64]
    float* out = (float*)d_out;                   // [4,256,64,64]
    float* att = (float*)d_out + 4194304;         // [4][4356][4096] position-major
    float* rn = (float*)d_ws;                     // 16384 f32
    _Float16* Kcl = (_Float16*)(rn + 16384);      // [4][256][4096] fp16
    _Float16* Klc = Kcl + (size_t)BZ * NC * LDIM; // [4][4096][256] fp16
    float* PoolF = (float*)(Klc + (size_t)BZ * NC * LDIM);  // [4][256][4356] f32
    _Float16* Pm16 = (_Float16*)(PoolF + (size_t)BZ * NC * P66);  // [4][4356][256] fp16

    rnorm_kernel<<<64, 256, 0, stream>>>(x, rn);
    kconv_kernel<<<dim3(64, 4, BZ), 256, 0, stream>>>(x, rn, Kcl, Klc);
    pool_kernel<<<17424, 256, 0, stream>>>(x, PoolF);
    ptrans_kernel<<<dim3(69, 4, BZ), 256, 0, stream>>>(PoolF, Pm16);
    gemm1_mfma<<<dim3(32, 35, BZ), 256, 0, stream>>>(Pm16, Klc, att);
    softmax_kernel<<<17424, 256, 0, stream>>>(att);
    gemm2_mfma<<<dim3(2, 128, BZ), 256, 0, stream>>>(Kcl, att, out);
}

// Round 3
// 653.618 us; speedup vs baseline: 1.0067x; 1.0067x over previous
//
#include <hip/hip_runtime.h>
#include <math.h>
#include <stdint.h>

#define LDIM 4096   // L = 64*64
#define NC   256
#define W66  66
#define P66  4356   // 66*66
#define BZ   4
#define EPSK 1e-7f

typedef _Float16 v8h __attribute__((ext_vector_type(8)));
typedef float v4f __attribute__((ext_vector_type(4)));

__device__ __forceinline__ void cp16(const void* g, void* l) {
    __builtin_amdgcn_global_load_lds(
        (const __attribute__((address_space(1))) void*)g,
        (__attribute__((address_space(3))) void*)l, 16, 0, 0);
}

// ---------------- rnorm: 1/||x[:,l]+eps|| per (b,l) ----------------
// 256 blocks (4x parallelism vs before): block = (b, 64-l chunk); 4 c-groups x 64 lanes.
__global__ __launch_bounds__(256) void rnorm_kernel(const float* __restrict__ x,
                                                    float* __restrict__ rnorm) {
    __shared__ float part[4][64];
    int blk = blockIdx.x;             // 0..255
    int b = blk >> 6;
    int l0 = (blk & 63) << 6;
    int lane = threadIdx.x & 63, cg = threadIdx.x >> 6;
    const float* xb = x + (size_t)b * NC * LDIM + l0 + lane;
    float s = 0.f;
#pragma unroll 8
    for (int c = cg * 64; c < cg * 64 + 64; ++c) {
        float v = xb[(size_t)c * LDIM] + EPSK;
        s += v * v;
    }
    part[cg][lane] = s;
    __syncthreads();
    if (cg == 0) {
        float t = part[0][lane] + part[1][lane] + part[2][lane] + part[3][lane];
        rnorm[b * LDIM + l0 + lane] = 1.0f / sqrtf(t);
    }
}

// ---------------- kconv: Kcl[b][c][l] fp16 and Klc[b][l][c] fp16 ----------------
__global__ __launch_bounds__(256) void kconv_kernel(const float* __restrict__ x,
                                                    const float* __restrict__ rn,
                                                    _Float16* __restrict__ Kcl,
                                                    _Float16* __restrict__ Klc) {
    __shared__ _Float16 t[64][72];
    int b = blockIdx.z, c0 = blockIdx.y * 64, l0 = blockIdx.x * 64;
    int tid = threadIdx.x;
    int r = tid >> 2, q = (tid & 3) * 16;
    const float* xr = x + ((size_t)(b * NC + c0 + r)) * LDIM + l0 + q;
    const float* rr = rn + b * LDIM + l0 + q;
    const float4* xr4 = (const float4*)xr;
    const float4* rr4 = (const float4*)rr;
    _Float16 h[16];
#pragma unroll
    for (int j4 = 0; j4 < 4; ++j4) {
        float4 a = xr4[j4];
        float4 w = rr4[j4];
        h[j4 * 4 + 0] = (_Float16)((a.x + EPSK) * w.x);
        h[j4 * 4 + 1] = (_Float16)((a.y + EPSK) * w.y);
        h[j4 * 4 + 2] = (_Float16)((a.z + EPSK) * w.z);
        h[j4 * 4 + 3] = (_Float16)((a.w + EPSK) * w.w);
    }
    _Float16* kc = Kcl + ((size_t)(b * NC + c0 + r)) * LDIM + l0 + q;
    *(v8h*)kc = *(v8h*)h;
    *(v8h*)(kc + 8) = *(v8h*)(h + 8);
#pragma unroll
    for (int j = 0; j < 16; ++j) t[r][q + j] = h[j];
    __syncthreads();
    _Float16 g[16];
#pragma unroll
    for (int j = 0; j < 16; ++j) g[j] = t[q + j][r];
    _Float16* kl = Klc + ((size_t)(b * LDIM + l0 + r)) * NC + c0 + q;
    *(v8h*)kl = *(v8h*)g;
    *(v8h*)(kl + 8) = *(v8h*)(g + 8);
}

// ---------------- pool: PoolF[b][c][p] fp32, 3x3 clipped sum (separable, LDS) ----------------
// One block per (b,c) image: float4 image load -> LDS, row-wise 3-sum, col-wise 3-sum,
// coalesced writes. Replaces per-thread 9-window loop with / and %.
__global__ __launch_bounds__(256) void pool_kernel(const float* __restrict__ x,
                                                   float* __restrict__ Pm) {
    __shared__ float img[64][68];
    __shared__ float rs[64][68];
    int bc = blockIdx.x;                       // 0..BZ*NC-1
    const float* xbc = x + (size_t)bc * LDIM;
    int tid = threadIdx.x;
#pragma unroll
    for (int it = 0; it < 4; ++it) {
        int o = tid + it * 256;                // float4 index 0..1023
        float4 vv = ((const float4*)xbc)[o];
        int u = o >> 4, j4 = (o & 15) << 2;
        img[u][j4] = vv.x; img[u][j4 + 1] = vv.y; img[u][j4 + 2] = vv.z; img[u][j4 + 3] = vv.w;
    }
    __syncthreads();
    {
        int u = tid >> 2, g = tid & 3;
        int v0 = g * 17, v1 = v0 + 17; if (v1 > 66) v1 = 66;
        const float* row = img[u];
        for (int v = v0; v < v1; ++v) {
            int j0 = v - 2; if (j0 < 0) j0 = 0;
            int j1 = v; if (j1 > 63) j1 = 63;
            float s = 0.f;
            for (int j = j0; j <= j1; ++j) s += row[j];
            rs[u][v] = s;
        }
    }
    __syncthreads();
    float* Pout = Pm + (size_t)bc * P66;
    for (int p = tid; p < P66; p += 256) {
        int uu = p / W66, v = p - uu * W66;
        int i0 = uu - 2; if (i0 < 0) i0 = 0;
        int i1 = uu; if (i1 > 63) i1 = 63;
        float s = 0.f;
        for (int i = i0; i <= i1; ++i) s += rs[i][v];
        Pout[p] = s;
    }
}

// ---------------- ptrans: Pm16[b][p][c] fp16 = transpose(PoolF) ----------------
__global__ __launch_bounds__(256) void ptrans_kernel(const float* __restrict__ PoolF,
                                                     _Float16* __restrict__ Pm16) {
    __shared__ float t[64][65];
    int b = blockIdx.z, c0 = blockIdx.y * 64, p0 = blockIdx.x * 64;
    int tid = threadIdx.x;
    int r = tid >> 2, q = (tid & 3) * 16;
    const float* src = PoolF + ((size_t)(b * NC + c0 + r)) * P66 + p0 + q;
    const float4* s4 = (const float4*)src;     // 16B-aligned (P66 % 4 == 0)
#pragma unroll
    for (int j4 = 0; j4 < 4; ++j4) {           // overread lands in next ws region (safe)
        float4 a = s4[j4];
        t[r][q + j4 * 4 + 0] = a.x; t[r][q + j4 * 4 + 1] = a.y;
        t[r][q + j4 * 4 + 2] = a.z; t[r][q + j4 * 4 + 3] = a.w;
    }
    __syncthreads();
    if (p0 + r < P66) {
        _Float16 g[16];
#pragma unroll
        for (int j = 0; j < 16; ++j) g[j] = (_Float16)t[q + j][r];
        _Float16* dst = Pm16 + ((size_t)(b * P66 + p0 + r)) * NC + c0 + q;
        *(v8h*)dst = *(v8h*)g;
        *(v8h*)(dst + 8) = *(v8h*)(g + 8);
    }
}

// ---------------- GEMM1 (MFMA fp16): S[p][l] = sum_c Pm16[p][c]*Klc[l][c] ----------------
__global__ __launch_bounds__(256) void gemm1_mfma(const _Float16* __restrict__ Pm16,
                                                  const _Float16* __restrict__ Klc,
                                                  float* __restrict__ S) {
    __shared__ _Float16 As[128 * 32];
    __shared__ _Float16 Bs[128 * 32];
    int b = blockIdx.z;
    int p0 = blockIdx.y * 128;
    int l0 = blockIdx.x * 128;
    const _Float16* A = Pm16 + (size_t)b * P66 * NC;
    const _Float16* B = Klc + (size_t)b * LDIM * NC;
    float* C = S + (size_t)b * P66 * LDIM;
    int tid = threadIdx.x;
    int lane = tid & 63, wave = tid >> 6;
    int wm = (wave >> 1) * 64, wn = (wave & 1) * 64;
    int quad = lane >> 4, hn = lane & 15;
    int sr = tid >> 2, sk = (tid & 3) * 8;
    int pa0 = p0 + sr;      if (pa0 > P66 - 1) pa0 = P66 - 1;
    int pa1 = p0 + sr + 64; if (pa1 > P66 - 1) pa1 = P66 - 1;
    const _Float16* Ag0 = A + (size_t)pa0 * NC + sk;
    const _Float16* Ag1 = A + (size_t)pa1 * NC + sk;
    const _Float16* Bg0 = B + (size_t)(l0 + sr) * NC + sk;
    const _Float16* Bg1 = B + (size_t)(l0 + sr + 64) * NC + sk;
    char* lA = (char*)As + tid * 16;
    char* lB = (char*)Bs + tid * 16;
    v4f acc[4][4];
    v4f vz = {0.f, 0.f, 0.f, 0.f};
#pragma unroll
    for (int i = 0; i < 4; ++i)
#pragma unroll
        for (int j = 0; j < 4; ++j) acc[i][j] = vz;

    for (int k0 = 0; k0 < NC; k0 += 32) {
        __syncthreads();
        cp16(Ag0 + k0, lA);
        cp16(Ag1 + k0, lA + 4096);
        cp16(Bg0 + k0, lB);
        cp16(Bg1 + k0, lB + 4096);
        __syncthreads();
        v8h af[4], bfr[4];
#pragma unroll
        for (int t = 0; t < 4; ++t)
            af[t] = *(const v8h*)(As + (wm + t * 16 + hn) * 32 + quad * 8);
#pragma unroll
        for (int t = 0; t < 4; ++t)
            bfr[t] = *(const v8h*)(Bs + (wn + t * 16 + hn) * 32 + quad * 8);
#pragma unroll
        for (int i = 0; i < 4; ++i)
#pragma unroll
            for (int j = 0; j < 4; ++j)
                acc[i][j] = __builtin_amdgcn_mfma_f32_16x16x32_f16(af[i], bfr[j], acc[i][j], 0, 0, 0);
    }
#pragma unroll
    for (int i = 0; i < 4; ++i) {
        int pr = p0 + wm + i * 16 + quad * 4;
#pragma unroll
        for (int j = 0; j < 4; ++j) {
            int lc = l0 + wn + j * 16 + hn;
            float* Cp = C + (size_t)pr * LDIM + lc;
#pragma unroll
            for (int r = 0; r < 4; ++r)
                if (pr + r < P66) Cp[(size_t)r * LDIM] = acc[i][j][r];
        }
    }
}

// ---------------- softmax over l, in place on att rows ----------------
__global__ __launch_bounds__(256) void softmax_kernel(float* __restrict__ att) {
    float* row = att + (size_t)blockIdx.x * LDIM;
    int tid = threadIdx.x;
    float4 v[4];
    float mx = -1e30f;
#pragma unroll
    for (int i = 0; i < 4; ++i) {
        v[i] = ((float4*)row)[tid + i * 256];
        mx = fmaxf(mx, fmaxf(fmaxf(v[i].x, v[i].y), fmaxf(v[i].z, v[i].w)));
    }
    __shared__ float sred[4];
    __shared__ float ssum[4];
#pragma unroll
    for (int off = 32; off > 0; off >>= 1) mx = fmaxf(mx, __shfl_xor(mx, off));
    if ((tid & 63) == 0) sred[tid >> 6] = mx;
    __syncthreads();
    float m4 = fmaxf(fmaxf(sred[0], sred[1]), fmaxf(sred[2], sred[3]));
    float sum = 0.f;
#pragma unroll
    for (int i = 0; i < 4; ++i) {
        v[i].x = __expf(v[i].x - m4);
        v[i].y = __expf(v[i].y - m4);
        v[i].z = __expf(v[i].z - m4);
        v[i].w = __expf(v[i].w - m4);
        sum += (v[i].x + v[i].y) + (v[i].z + v[i].w);
    }
#pragma unroll
    for (int off = 32; off > 0; off >>= 1) sum += __shfl_xor(sum, off);
    if ((tid & 63) == 0) ssum[tid >> 6] = sum;
    __syncthreads();
    float r = 1.0f / (ssum[0] + ssum[1] + ssum[2] + ssum[3]);
#pragma unroll
    for (int i = 0; i < 4; ++i) {
        v[i].x *= r; v[i].y *= r; v[i].z *= r; v[i].w *= r;
        ((float4*)row)[tid + i * 256] = v[i];
    }
}

// ---------------- GEMM2 (MFMA fp16): out[c][i] = sum_l Kcl[c][l]*att[p(i)][l] ----------------
// BK=128: 12 global_load_lds (48 KB) in flight per barrier-drain (4x the MLP of BK=32),
// 32 iterations instead of 128. LDS = 32+16 KB -> 3 blocks/CU. A in 4 column-slabs
// [128][32] fp16; B in 4 slabs [32][32] f32, XOR-swizzled via pre-swizzled global source.
__global__ __launch_bounds__(256) void gemm2_mfma(const _Float16* __restrict__ Kcl,
                                                  const float* __restrict__ attF,
                                                  float* __restrict__ outp) {
    __shared__ _Float16 As[4][128 * 32];   // 4 x 8 KiB
    __shared__ float BsF[4][32 * 32];      // 4 x 4 KiB
    int b = blockIdx.z;
    int c0 = blockIdx.x * 128;
    int i0 = blockIdx.y * 32;
    const _Float16* A = Kcl + (size_t)b * NC * LDIM;
    const float* Batt = attF + (size_t)b * P66 * LDIM;
    float* C = outp + (size_t)b * NC * LDIM;
    int tid = threadIdx.x;
    int lane = tid & 63, wave = tid >> 6;
    int wm = (wave >> 1) * 64, wn = (wave & 1) * 16;
    int quad = lane >> 4, hn = lane & 15;
    int sr = tid >> 2, sk = (tid & 3) * 8;
    const _Float16* Ag = A + (size_t)(c0 + sr) * LDIM + sk;
    int br = tid >> 3;
    int bo = (((tid & 7) ^ (br & 7)) << 2);      // swizzled source float offset
    int ii = i0 + br;
    int p = ((ii >> 6) + 1) * W66 + (ii & 63) + 1;
    const float* Bg = Batt + (size_t)p * LDIM + bo;
    char* lA = (char*)As + tid * 16;
    char* lB = (char*)BsF + tid * 16;
    v4f acc[4];
    v4f vz = {0.f, 0.f, 0.f, 0.f};
#pragma unroll
    for (int i = 0; i < 4; ++i) acc[i] = vz;

    for (int k0 = 0; k0 < LDIM; k0 += 128) {
        __syncthreads();
#pragma unroll
        for (int j = 0; j < 4; ++j) {
            cp16(Ag + k0 + j * 32, lA + j * 8192);
            cp16(Ag + (size_t)64 * LDIM + k0 + j * 32, lA + j * 8192 + 4096);
            cp16(Bg + k0 + j * 32, lB + j * 4096);
        }
        __syncthreads();
#pragma unroll
        for (int j = 0; j < 4; ++j) {
            const _Float16* Asl = (const _Float16*)As + j * 4096;
            const float* Bsl = (const float*)BsF + j * 1024;
            v8h af[4];
#pragma unroll
            for (int t = 0; t < 4; ++t)
                af[t] = *(const v8h*)(Asl + (wm + t * 16 + hn) * 32 + quad * 8);
            int brow = wn + hn;                      // 0..31
            int s0 = ((quad * 2 + 0) ^ (brow & 7)) << 2;
            int s1 = ((quad * 2 + 1) ^ (brow & 7)) << 2;
            v4f x0 = *(const v4f*)(Bsl + brow * 32 + s0);
            v4f x1 = *(const v4f*)(Bsl + brow * 32 + s1);
            v8h bfr;
#pragma unroll
            for (int jj = 0; jj < 4; ++jj) { bfr[jj] = (_Float16)x0[jj]; bfr[jj + 4] = (_Float16)x1[jj]; }
#pragma unroll
            for (int i = 0; i < 4; ++i)
                acc[i] = __builtin_amdgcn_mfma_f32_16x16x32_f16(af[i], bfr, acc[i], 0, 0, 0);
        }
    }
#pragma unroll
    for (int i = 0; i < 4; ++i) {
        int cr = c0 + wm + i * 16 + quad * 4;
        int ic = i0 + wn + hn;
        float* Cp = C + (size_t)cr * LDIM + ic;
#pragma unroll
        for (int r = 0; r < 4; ++r)
            Cp[(size_t)r * LDIM] = acc[i][r];
    }
}

extern "C" void kernel_launch(void* const* d_in, const int* in_sizes, int n_in,
                              void* d_out, int out_size, void* d_ws, size_t ws_size,
                              hipStream_t stream) {
    const float* x = (const float*)d_in[0];       // [4,256,64,64]
    float* out = (float*)d_out;                   // [4,256,64,64]
    float* att = (float*)d_out + 4194304;         // [4][4356][4096] position-major
    float* rn = (float*)d_ws;                     // 16384 f32
    _Float16* Kcl = (_Float16*)(rn + 16384);      // [4][256][4096] fp16
    _Float16* Klc = Kcl + (size_t)BZ * NC * LDIM; // [4][4096][256] fp16
    float* PoolF = (float*)(Klc + (size_t)BZ * NC * LDIM);  // [4][256][4356] f32
    _Float16* Pm16 = (_Float16*)(PoolF + (size_t)BZ * NC * P66);  // [4][4356][256] fp16

    rnorm_kernel<<<256, 256, 0, stream>>>(x, rn);
    kconv_kernel<<<dim3(64, 4, BZ), 256, 0, stream>>>(x, rn, Kcl, Klc);
    pool_kernel<<<BZ * NC, 256, 0, stream>>>(x, PoolF);
    ptrans_kernel<<<dim3(69, 4, BZ), 256, 0, stream>>>(PoolF, Pm16);
    gemm1_mfma<<<dim3(32, 35, BZ), 256, 0, stream>>>(Pm16, Klc, att);
    softmax_kernel<<<17424, 256, 0, stream>>>(att);
    gemm2_mfma<<<dim3(2, 128, BZ), 256, 0, stream>>>(Kcl, att, out);
}